// Round 10
// baseline (210.387 us; speedup 1.0000x reference)
//
#include <hip/hip_runtime.h>
#include <math.h>

// Problem constants: B=4, L=T=2048, H=8, E=64, C=H*E=512, top_k=7
// Output = cumsum(V) with top-7 rows (by corrmean) replaced by running mean.
// Only the top-7 index SET of corrmean affects the output -> grams in bf16
// MFMA. Temporal LSE uses fixed exp-offset 80; sum-only partials.
// R6: symmetric gram -> upper-triangle tiles only (528/1024 per batch).
// R8: pipelined temporal (neutral vs R6 -- 60.5us, barrier-bound structure;
//     parked) + XCD swizzle (FETCH 80->24MB, confirmed).
// R9: the OTHER 133us: (1) cumsum was 32 blocks = 32 CUs (~40us latency-
//     bound) -> two-kernel grid-512 version (~10us); (2) instance fused
//     into convert via blockIdx branch (reads fp32 directly, same f2bf ->
//     bit-identical), one fewer launch.

typedef __attribute__((ext_vector_type(8))) short short8;
typedef __attribute__((ext_vector_type(8))) unsigned short ushort8;
typedef __attribute__((ext_vector_type(4))) float f32x4;

typedef const __attribute__((address_space(1))) void* gas_ptr;
typedef __attribute__((address_space(3))) void* las_ptr;

#define EXP_OFF 80.0f

__device__ __forceinline__ void async_cp16(const void* g, void* l) {
  // LDS dest is wave-uniform base; HW adds lane*16 (m104/m108).
  __builtin_amdgcn_global_load_lds((gas_ptr)g, (las_ptr)l, 16, 0, 0);
}

__device__ __forceinline__ unsigned short f2bf(float x) {
  union { float f; unsigned int u; } v; v.f = x;
  unsigned int r = v.u + 0x7FFFu + ((v.u >> 16) & 1u);  // RNE
  return (unsigned short)(r >> 16);
}

// ---------------------------------------------------------------------------
// Fused: blocks [0,4096) convert Q,K fp32 -> Z bf16 [4][4096][512];
// blocks [4096,4352) compute instance LSE + posdot via MFMA, reading fp32
// directly with inline f2bf (bit-identical to Z, no dependency on convert).
// ---------------------------------------------------------------------------
__global__ __launch_bounds__(256) void conv_inst_kernel(
    const float* __restrict__ Q, const float* __restrict__ K,
    unsigned short* __restrict__ Z,
    float* __restrict__ lse_inst /* [2048][8] */,
    float* __restrict__ posdot /* [4][2048] */) {
  if (blockIdx.x < 4096) {
    int tid = blockIdx.x * 256 + threadIdx.x;  // 0..1048575
    int row = tid >> 6;                        // b*4096 + i
    int c0 = (tid & 63) * 8;
    int b = row >> 12, i = row & 4095;
    const float* src = (i < 2048)
        ? Q + ((size_t)(b * 2048 + i) * 512 + c0)
        : K + ((size_t)(b * 2048 + (i - 2048)) * 512 + c0);
    float4 v0 = ((const float4*)src)[0];
    float4 v1 = ((const float4*)src)[1];
    ushort8 o;
    o[0] = f2bf(v0.x); o[1] = f2bf(v0.y); o[2] = f2bf(v0.z); o[3] = f2bf(v0.w);
    o[4] = f2bf(v1.x); o[5] = f2bf(v1.y); o[6] = f2bf(v1.z); o[7] = f2bf(v1.w);
    *(ushort8*)(Z + (size_t)row * 512 + c0) = o;
    return;
  }
  // ---- instance path: one wave per t-pair, gram via A=B MFMA trick ----
  int wave = ((blockIdx.x - 4096) * 256 + threadIdx.x) >> 6;  // 0..1023
  int t0 = wave * 2;
  int lane = threadIdx.x & 63;
  int lm = lane & 15, q = lane >> 4;
  int tt = (lm < 8) ? t0 : t0 + 1;
  int v = lm & 7;
  // row v<4: Q[b=v, tt]; else K[b=v-4, tt] -- fp32 source
  const float* g = ((v < 4) ? Q + ((size_t)v * 2048 + tt) * 512
                            : K + ((size_t)(v - 4) * 2048 + tt) * 512) + q * 8;

  f32x4 acc0 = (f32x4)(0.f), acc1 = (f32x4)(0.f);
#pragma unroll
  for (int kc = 0; kc < 16; kc += 2) {
    float4 x0 = ((const float4*)(g + kc * 32))[0];
    float4 x1 = ((const float4*)(g + kc * 32))[1];
    float4 y0 = ((const float4*)(g + kc * 32 + 32))[0];
    float4 y1 = ((const float4*)(g + kc * 32 + 32))[1];
    short8 a0, a1;
    a0[0] = (short)f2bf(x0.x); a0[1] = (short)f2bf(x0.y);
    a0[2] = (short)f2bf(x0.z); a0[3] = (short)f2bf(x0.w);
    a0[4] = (short)f2bf(x1.x); a0[5] = (short)f2bf(x1.y);
    a0[6] = (short)f2bf(x1.z); a0[7] = (short)f2bf(x1.w);
    a1[0] = (short)f2bf(y0.x); a1[1] = (short)f2bf(y0.y);
    a1[2] = (short)f2bf(y0.z); a1[3] = (short)f2bf(y0.w);
    a1[4] = (short)f2bf(y1.x); a1[5] = (short)f2bf(y1.y);
    a1[6] = (short)f2bf(y1.z); a1[7] = (short)f2bf(y1.w);
    acc0 = __builtin_amdgcn_mfma_f32_16x16x32_bf16(a0, a0, acc0, 0, 0, 0);
    acc1 = __builtin_amdgcn_mfma_f32_16x16x32_bf16(a1, a1, acc1, 0, 0, 0);
  }
  f32x4 acc = acc0 + acc1;

#pragma unroll
  for (int rr = 0; rr < 4; rr++) {
    int i = q * 4 + rr;                      // row 0..15
    float val = acc[rr];
    bool samehalf = ((i < 8) == (lm < 8));
    int t = (i < 8) ? t0 : t0 + 1;
    int iv = i & 7;
    if (samehalf && iv < 4 && (lm & 7) == iv + 4)
      posdot[iv * 2048 + t] = val;
    float dd = (samehalf && lm != i) ? val : -INFINITY;
    float mt = dd;
    mt = fmaxf(mt, __shfl_xor(mt, 1));
    mt = fmaxf(mt, __shfl_xor(mt, 2));
    mt = fmaxf(mt, __shfl_xor(mt, 4));
    float e = __expf(dd - mt);
    e += __shfl_xor(e, 1);
    e += __shfl_xor(e, 2);
    e += __shfl_xor(e, 4);
    if ((lm & 7) == 0 && samehalf) lse_inst[t * 8 + iv] = mt + __logf(e);
  }
}

// ---------------------------------------------------------------------------
// Temporal gram, upper-triangle tiles (ri<=cj), 128x128, 16x16x32 bf16 MFMA,
// BK=32, double-buffered LDS (one barrier per kc), XOR-swizzled staging
// (SQ_LDS_BANK_CONFLICT=0 verified). XCD-pair swizzle: b=(id&7)>>1.
// UNCHANGED from R8 (verified at 60.5us).
// ---------------------------------------------------------------------------
__global__ __launch_bounds__(256, 3) void temporal_gemm_kernel(
    const unsigned short* __restrict__ Z, float* __restrict__ part) {
  int id = blockIdx.x;                  // 0..2111
  int x = id & 7;
  int b = x >> 1;                       // XCD-pair lock per batch
  int t = (id >> 3) * 2 + (x & 1);      // 0..527
  // invert t = cj*(cj+1)/2 + ri, ri<=cj
  int cj = (int)((sqrtf(8.0f * (float)t + 1.0f) - 1.0f) * 0.5f);
  while ((cj + 1) * (cj + 2) / 2 <= t) cj++;
  while (cj * (cj + 1) / 2 > t) cj--;
  int ri = t - cj * (cj + 1) / 2;
  const unsigned short* Zb = Z + (size_t)b * 4096 * 512;

  __shared__ __align__(16) unsigned short As[2][128 * 32];  // 2 x 8 KB
  __shared__ __align__(16) unsigned short Bs[2][128 * 32];  // 2 x 8 KB

  int tid = threadIdx.x;
  int w = tid >> 6, lane = tid & 63;
  int wr = w >> 1, wc = w & 1;
  int lm = lane & 15, q = lane >> 4;
  int swz = q ^ ((lm >> 1) & 3);  // frag-read physical chunk

  int srow = lane >> 2;
  int kq = (lane & 3) ^ ((lane >> 3) & 3);
  int rl0 = w * 16 + srow;
  int rl1 = 64 + rl0;
  const unsigned short* gA0 = Zb + (size_t)(ri * 128 + rl0) * 512 + kq * 8;
  const unsigned short* gA1 = Zb + (size_t)(ri * 128 + rl1) * 512 + kq * 8;
  const unsigned short* gB0 = Zb + (size_t)(cj * 128 + rl0) * 512 + kq * 8;
  const unsigned short* gB1 = Zb + (size_t)(cj * 128 + rl1) * 512 + kq * 8;
  int lo0 = (w * 16) * 32;        // wave-uniform base offsets
  int lo1 = (64 + w * 16) * 32;

  f32x4 acc[4][4];
#pragma unroll
  for (int mi = 0; mi < 4; mi++)
#pragma unroll
    for (int ni = 0; ni < 4; ni++) acc[mi][ni] = (f32x4)(0.f);

  // Prologue: stage kc=0 into buffer 0.
  async_cp16(gA0, As[0] + lo0);
  async_cp16(gA1, As[0] + lo1);
  async_cp16(gB0, Bs[0] + lo0);
  async_cp16(gB1, Bs[0] + lo1);

  for (int kc = 0; kc < 16; ++kc) {
    int cur = kc & 1;
    __syncthreads();  // drains stage(kc) — issued one compute phase ago

    if (kc < 15) {
      int go = (kc + 1) * 32;
      async_cp16(gA0 + go, As[cur ^ 1] + lo0);
      async_cp16(gA1 + go, As[cur ^ 1] + lo1);
      async_cp16(gB0 + go, Bs[cur ^ 1] + lo0);
      async_cp16(gB1 + go, Bs[cur ^ 1] + lo1);
    }

    short8 af[4], bfr[4];
#pragma unroll
    for (int mi = 0; mi < 4; mi++) {
      int ar = wr * 64 + mi * 16 + lm;
      af[mi] = *(const short8*)(As[cur] + ar * 32 + swz * 8);
    }
#pragma unroll
    for (int ni = 0; ni < 4; ni++) {
      int bc = wc * 64 + ni * 16 + lm;
      bfr[ni] = *(const short8*)(Bs[cur] + bc * 32 + swz * 8);
    }
#pragma unroll
    for (int mi = 0; mi < 4; mi++)
#pragma unroll
      for (int ni = 0; ni < 4; ni++)
        acc[mi][ni] = __builtin_amdgcn_mfma_f32_16x16x32_bf16(
            af[mi], bfr[ni], acc[mi][ni], 0, 0, 0);
  }

  // Epilogue. C/D layout: col=lane&15, row=(lane>>4)*4+reg (m89-verified).
  float rsum[4][4];
  float csum[4];
#pragma unroll
  for (int mi = 0; mi < 4; mi++)
#pragma unroll
    for (int rr = 0; rr < 4; rr++) rsum[mi][rr] = 0.f;
#pragma unroll
  for (int ni = 0; ni < 4; ni++) csum[ni] = 0.f;

#pragma unroll
  for (int mi = 0; mi < 4; mi++) {
#pragma unroll
    for (int ni = 0; ni < 4; ni++) {
#pragma unroll
      for (int rr = 0; rr < 4; rr++) {
        int R = ri * 128 + wr * 64 + mi * 16 + q * 4 + rr;
        int Cg = cj * 128 + wc * 64 + ni * 16 + lm;
        float e = (R != Cg) ? __expf(acc[mi][ni][rr] - EXP_OFF) : 0.f;
        rsum[mi][rr] += e;
        csum[ni] += e;
      }
    }
  }

#pragma unroll
  for (int mi = 0; mi < 4; mi++) {
#pragma unroll
    for (int rr = 0; rr < 4; rr++) {
      float s = rsum[mi][rr];
      s += __shfl_xor(s, 1);
      s += __shfl_xor(s, 2);
      s += __shfl_xor(s, 4);
      s += __shfl_xor(s, 8);
      if (lm == 0) {
        int R = ri * 128 + wr * 64 + mi * 16 + q * 4 + rr;
        part[((size_t)(b * 4096 + R)) * 64 + cj * 2 + wc] = s;
      }
    }
  }

  if (ri != cj) {
#pragma unroll
    for (int ni = 0; ni < 4; ni++) {
      float s = csum[ni];
      s += __shfl_xor(s, 16);
      s += __shfl_xor(s, 32);
      if (q == 0) {
        int Cg = cj * 128 + wc * 64 + ni * 16 + lm;
        part[((size_t)(b * 4096 + Cg)) * 64 + ri * 2 + wr] = s;
      }
    }
  }
}

// lse_temp[row] = 80 + log(sum of 64 partials). One thread per row.
__global__ __launch_bounds__(256) void merge_row_kernel(
    const float* __restrict__ part, float* __restrict__ lse_temp) {
  int row = blockIdx.x * 256 + threadIdx.x;  // 0..16383
  const float4* p = (const float4*)(part + (size_t)row * 64);
  float s = 0.f;
#pragma unroll
  for (int i = 0; i < 16; i++) {
    float4 v = p[i];
    s += v.x + v.y + v.z + v.w;
  }
  lse_temp[row] = EXP_OFF + __logf(s);
}

// ---------------------------------------------------------------------------
// Fused combine + top-7. One block; each thread owns 8 t's in registers.
// ---------------------------------------------------------------------------
__global__ __launch_bounds__(256) void combine_topk_kernel(
    const float* __restrict__ lse_inst, const float* __restrict__ lse_temp,
    const float* __restrict__ posdot, int* __restrict__ index_out) {
  __shared__ float wmax[4];
  __shared__ int widx[4];
  int tid = threadIdx.x;
  int base = tid * 8;
  float v[8];
#pragma unroll
  for (int r = 0; r < 8; r++) {
    int t = base + r;
    float sum = 0.f;
#pragma unroll
    for (int b = 0; b < 4; b++) {
      sum += 0.25f * (lse_inst[t * 8 + b] + lse_inst[t * 8 + 4 + b] +
                      lse_temp[b * 4096 + t] + lse_temp[b * 4096 + 2048 + t]) -
             posdot[b * 2048 + t];
    }
    v[r] = sum * 0.25f;
  }
  int lane = tid & 63, w = tid >> 6;
  for (int k = 0; k < 7; k++) {
    float bv = v[0];
    int bi = base;
#pragma unroll
    for (int r = 1; r < 8; r++)
      if (v[r] > bv) { bv = v[r]; bi = base + r; }
#pragma unroll
    for (int d = 1; d < 64; d <<= 1) {
      float ov = __shfl_xor(bv, d);
      int oi = __shfl_xor(bi, d);
      if (ov > bv || (ov == bv && oi < bi)) { bv = ov; bi = oi; }
    }
    if (lane == 0) { wmax[w] = bv; widx[w] = bi; }
    __syncthreads();
    float BV = wmax[0];
    int BI = widx[0];
#pragma unroll
    for (int ww = 1; ww < 4; ww++)
      if (wmax[ww] > BV || (wmax[ww] == BV && widx[ww] < BI)) {
        BV = wmax[ww];
        BI = widx[ww];
      }
    if (tid == 0) index_out[k] = BI;
    if (BI >= base && BI < base + 8) v[BI - base] = -INFINITY;
    __syncthreads();
  }
}

// ---------------------------------------------------------------------------
// Cumsum, re-parallelized: grid 512 = (bh 0..31) x (chunk 0..15), 256 thr =
// (sub 0..3) x (e 0..63); each (chunk,sub) covers 32 L rows.
// k1: spart[bh*64 + chunk*4 + sub][e] = sum of its 32 rows.
// k2: prefix over preceding (chunk,sub) partials (L2-hot), rewalk 32 rows,
//     selected rows -> running mean.
// ---------------------------------------------------------------------------
__global__ __launch_bounds__(256) void cumsum_part_kernel(
    const float* __restrict__ V, float* __restrict__ spart) {
  int blk = blockIdx.x;                 // bh*16 + chunk
  int chunk = blk & 15, bh = blk >> 4;
  int h = bh & 7, b = bh >> 3;
  int tid = threadIdx.x;
  int e = tid & 63, sub = tid >> 6;
  const float* Vb = V + (size_t)b * 1048576 + h * 64 + e;
  int l0 = chunk * 128 + sub * 32;
  float s = 0.f;
  for (int l = l0; l < l0 + 32; ++l) s += Vb[(size_t)l * 512];
  spart[(size_t)(bh * 64 + chunk * 4 + sub) * 64 + e] = s;
}

__global__ __launch_bounds__(256) void cumsum_write_kernel(
    const float* __restrict__ V, const float* __restrict__ spart,
    const int* __restrict__ index, float* __restrict__ out) {
  int blk = blockIdx.x;
  int chunk = blk & 15, bh = blk >> 4;
  int h = bh & 7, b = bh >> 3;
  int tid = threadIdx.x;
  int e = tid & 63, sub = tid >> 6;
  const float* Vb = V + (size_t)b * 1048576 + h * 64 + e;
  float* ob = out + (size_t)bh * 131072 + e;

  int lin = chunk * 4 + sub;            // 0..63
  float run = 0.f;
  for (int p = 0; p < lin; ++p)
    run += spart[(size_t)(bh * 64 + p) * 64 + e];

  int idx[7];
#pragma unroll
  for (int k = 0; k < 7; k++) idx[k] = index[k];

  int l0 = chunk * 128 + sub * 32;
  for (int l = l0; l < l0 + 32; ++l) {
    run += Vb[(size_t)l * 512];
    float o = run;
    bool special = false;
#pragma unroll
    for (int k = 0; k < 7; k++) special = special || (idx[k] == l);
    if (special) o = run / (float)(l + 1);
    ob[(size_t)l * 64] = o;
  }
}

extern "C" void kernel_launch(void* const* d_in, const int* in_sizes, int n_in,
                              void* d_out, int out_size, void* d_ws, size_t ws_size,
                              hipStream_t stream) {
  const float* Q = (const float*)d_in[0];  // (4,2048,512)
  const float* K = (const float*)d_in[1];
  const float* V = (const float*)d_in[2];
  float* out = (float*)d_out;              // (4,8,2048,64)

  // Workspace layout:
  unsigned short* Z = (unsigned short*)d_ws;        // 4*4096*512 bf16 = 16.8 MB
  float* base = (float*)d_ws + 4 * 4096 * 512 / 2;  // after Z
  float* part = base;                               // 4*4096*64 = 1M floats
  float* lse_t = base + 4 * 4096 * 64;              // 16384
  float* lse_i = lse_t + 16384;                     // 16384
  float* posd = lse_i + 16384;                      // 8192
  int* idx = (int*)(posd + 8192);                   // 8
  float* spart = posd + 8192 + 8;                   // 32*64*64 = 131072

  conv_inst_kernel<<<4096 + 256, 256, 0, stream>>>(Q, K, Z, lse_i, posd);
  temporal_gemm_kernel<<<4 * 528, 256, 0, stream>>>(Z, part);
  merge_row_kernel<<<64, 256, 0, stream>>>(part, lse_t);
  combine_topk_kernel<<<1, 256, 0, stream>>>(lse_i, lse_t, posd, idx);
  cumsum_part_kernel<<<512, 256, 0, stream>>>(V, spart);
  cumsum_write_kernel<<<512, 256, 0, stream>>>(V, spart, idx, out);
}